// Round 4
// baseline (374.111 us; speedup 1.0000x reference)
//
#include <hip/hip_runtime.h>
#include <hip/hip_cooperative_groups.h>

namespace cg = cooperative_groups;

// Problem constants
#define XDIM  100       // HK*BAG
#define DDIM  512
#define HDIM  512
#define NT    512
// ws layout (bytes)
#define WS_WT2   0          // fp16 Wt2[2][16][512][4][8]   = 1,048,576 B
#define WS_FEA16 1048576    // fp16 fea16[3200][512]        = 3,276,800 B
#define WS_V16   4325376    // fp16 v16[512]                = 1,024 B
#define WS_H16   4326400    // fp16 h16[3200][512]          = 3,276,800 B
#define WS_FP    7603200    // fp32 fp[8][16][100][100]     = 5,120,000 B
#define WS_FPS   12723200   // fp32 fps[16][100][100]       = 640,000 B

typedef _Float16 h16x8 __attribute__((ext_vector_type(8)));
typedef _Float16 h2    __attribute__((ext_vector_type(2)));
typedef float floatx4  __attribute__((ext_vector_type(4)));
typedef float floatx2  __attribute__((ext_vector_type(2)));

union H8U { h16x8 v; h2 p[4]; unsigned u[4]; };

// ---------------------------------------------------------------------------
// One cooperative kernel, 512 blocks x 256 threads, phases separated by
// grid.sync(). Eliminates 4 inter-kernel launch gaps of the 5-dispatch chain.
__global__ void __launch_bounds__(256, 2) fused_k(
    const float* __restrict__ fea,  const int* __restrict__ ind0,
    const int* __restrict__ ind1,   const float* __restrict__ W0,
    const float* __restrict__ W1,   const float* __restrict__ bias,
    const float* __restrict__ v,
    _Float16* __restrict__ Wt2,  _Float16* __restrict__ fea16,
    _Float16* __restrict__ v16,  _Float16* __restrict__ h16,
    float* __restrict__ fp,      float* __restrict__ fps,
    float* __restrict__ out,     float* __restrict__ pout)
{
    cg::grid_group grid = cg::this_grid();

    __shared__ _Float16 sh0[64][72];      // P2: [x][k], stride 72 (bank-safe)
    __shared__ unsigned sh1p[32][64];     // P2: [kpair][y] packed h2
    __shared__ unsigned sv[32];           // P2: v pairs
    __shared__ float rowsum[32][100];     // P4
    __shared__ int a0s[32], a1s[32];      // P4
    __shared__ int c0s[256], c1s[256];    // P4

    const int bx = blockIdx.x;
    const int t  = threadIdx.x;
    const int gtid = bx * 256 + t;        // 0..131071

    // ---- P0: prep (Wt2 fragment-ordered fp16 weights, fea16, v16) ----
    #pragma unroll
    for (int i = 0; i < 4; ++i) {
        int o  = gtid + i * 131072;       // 0..524287
        int w  = o >> 18;
        int kb = (o >> 14) & 15;
        int c  = (o >> 5) & 511;
        int qj = o & 31;
        int d  = kb * 32 + qj;
        const float* W = w ? W1 : W0;
        Wt2[o] = (_Float16)W[d * 512 + c];
    }
    for (int i = gtid; i < 409600; i += 131072) {
        float4 x = *(const float4*)(fea + (size_t)i * 4);
        _Float16 r[4] = {(_Float16)x.x, (_Float16)x.y, (_Float16)x.z, (_Float16)x.w};
        *(uint2*)(fea16 + (size_t)i * 4) = *(const uint2*)r;
    }
    if (gtid < 256) {
        v16[gtid * 2]     = (_Float16)v[gtid * 2];
        v16[gtid * 2 + 1] = (_Float16)v[gtid * 2 + 1];
    }
    grid.sync();

    // ---- P1: gemm, 64m x 64n tiles (512 blocks = 32 hb * 2 mt * 8 no) ----
    // 4 waves share the SAME 64 B-cols (L1/L2 reuse); rows mt*36+w*16 cover
    // 0..99 exactly; overlap rows recompute bit-identical values (benign).
    {
        int hb   = bx >> 4;
        int mt   = (bx >> 3) & 1;
        int no   = bx & 7;
        int w    = t >> 6;
        int lane = t & 63;
        int n0   = no * 64;
        int m0   = mt * 36 + w * 16;      // 0..84; +15 stays < 100
        int s    = hb & 1;
        int l15  = lane & 15;
        int q    = lane >> 4;

        const _Float16* ap = fea16 + (size_t)hb * (XDIM * DDIM) + (size_t)(m0 + l15) * DDIM + q * 8;
        const _Float16* bp = Wt2 + (size_t)s * 262144 + (size_t)(n0 + l15) * 32 + q * 8;

        floatx4 acc0 = {0.f, 0.f, 0.f, 0.f};
        floatx4 acc1 = acc0, acc2 = acc0, acc3 = acc0;

        for (int kb = 0; kb < 16; ++kb) {
            h16x8 a = *(const h16x8*)(ap + kb * 32);
            const _Float16* bkb = bp + kb * 16384;
            h16x8 b0 = *(const h16x8*)(bkb);
            h16x8 b1 = *(const h16x8*)(bkb + 512);
            h16x8 b2 = *(const h16x8*)(bkb + 1024);
            h16x8 b3 = *(const h16x8*)(bkb + 1536);
            acc0 = __builtin_amdgcn_mfma_f32_16x16x32_f16(a, b0, acc0, 0, 0, 0);
            acc1 = __builtin_amdgcn_mfma_f32_16x16x32_f16(a, b1, acc1, 0, 0, 0);
            acc2 = __builtin_amdgcn_mfma_f32_16x16x32_f16(a, b2, acc2, 0, 0, 0);
            acc3 = __builtin_amdgcn_mfma_f32_16x16x32_f16(a, b3, acc3, 0, 0, 0);
        }

        _Float16* hob = h16 + (size_t)hb * (XDIM * HDIM);
        #pragma unroll
        for (int j = 0; j < 4; ++j) {
            floatx4 a = (j == 0) ? acc0 : (j == 1) ? acc1 : (j == 2) ? acc2 : acc3;
            int col = n0 + 16 * j + l15;
            float bi = s ? bias[col] : 0.f;
            #pragma unroll
            for (int r = 0; r < 4; ++r) {
                int mr = m0 + q * 4 + r;  // always < 100
                hob[(size_t)mr * HDIM + col] = (_Float16)(a[r] + bi);
            }
        }
    }
    grid.sync();

    // ---- P2: full (exact R2 full_k: LDS stage, pout stream, dot2 compute) ----
    {
        int ks  = bx >> 6;
        int rem = bx & 63;
        int b   = rem >> 2;
        int xt  = (rem >> 1) & 1;
        int yt  = rem & 1;
        int x0  = xt * 36;                // tiles [0,64) and [36,100): overlap benign
        int y0  = yt * 36;
        int kc  = ks * 64;

        int r = t & 63, kseg = t >> 6;

        const _Float16* g0 = h16 + ((size_t)(b * 2) * XDIM + x0 + r) * HDIM + kc + kseg * 16;
        *(h16x8*)&sh0[r][kseg * 16]     = *(const h16x8*)g0;
        *(h16x8*)&sh0[r][kseg * 16 + 8] = *(const h16x8*)(g0 + 8);

        const _Float16* g1 = h16 + ((size_t)(b * 2 + 1) * XDIM + y0 + r) * HDIM + kc + kseg * 16;
        H8U u0, u1;
        u0.v = *(const h16x8*)g1;
        u1.v = *(const h16x8*)(g1 + 8);
        #pragma unroll
        for (int pp = 0; pp < 4; ++pp) {
            sh1p[kseg * 8 + pp][r]     = u0.u[pp];
            sh1p[kseg * 8 + 4 + pp][r] = u1.u[pp];
        }
        if (t < 32) sv[t] = *(const unsigned*)(v16 + kc + t * 2);
        __syncthreads();

        // pairs meshgrid: nontemporal streaming stores, drain under compute
        {
            size_t pbase = (size_t)bx * 8192;
            #pragma unroll 4
            for (int i = 0; i < 32; ++i) {
                unsigned idx = (unsigned)(pbase + i * 256 + t);
                floatx2 pr;
                pr.x = (float)((idx >> 9) & 511);
                pr.y = (float)(idx & 511);
                __builtin_nontemporal_store(pr, (floatx2*)(pout + (size_t)idx * 2));
            }
        }

        int ty = t >> 4, tx = t & 15;
        float acc[4][4] = {};
        h2 hz; hz[0] = (_Float16)0; hz[1] = (_Float16)0;

        for (int kk = 0; kk < 8; ++kk) {
            H8U a[4];
            #pragma unroll
            for (int i = 0; i < 4; ++i)
                a[i].v = *(const h16x8*)&sh0[ty * 4 + i][kk * 8];
            uint4 bq[4];
            #pragma unroll
            for (int p = 0; p < 4; ++p)
                bq[p] = *(const uint4*)&sh1p[kk * 4 + p][tx * 4];
            uint4 vq = *(const uint4*)&sv[kk * 4];
            const unsigned* vqa = (const unsigned*)&vq;

            #pragma unroll
            for (int p = 0; p < 4; ++p) {
                h2 vp = __builtin_bit_cast(h2, vqa[p]);
                const unsigned* bqa = (const unsigned*)&bq[p];
                #pragma unroll
                for (int i = 0; i < 4; ++i) {
                    h2 av = a[i].p[p];
                    #pragma unroll
                    for (int j = 0; j < 4; ++j) {
                        h2 s = av + __builtin_bit_cast(h2, bqa[j]);
                        s = __builtin_elementwise_max(s, hz);
#if __has_builtin(__builtin_amdgcn_fdot2)
                        acc[i][j] = __builtin_amdgcn_fdot2(s, vp, acc[i][j], false);
#else
                        acc[i][j] += (float)s[0] * (float)vp[0] + (float)s[1] * (float)vp[1];
#endif
                    }
                }
            }
        }

        float* fpb = fp + (size_t)(ks * 16 + b) * (XDIM * XDIM);
        #pragma unroll
        for (int i = 0; i < 4; ++i) {
            floatx4 o;
            o.x = acc[i][0]; o.y = acc[i][1]; o.z = acc[i][2]; o.w = acc[i][3];
            *(floatx4*)&fpb[(size_t)(x0 + ty * 4 + i) * XDIM + y0 + tx * 4] = o;
        }
    }
    grid.sync();

    // ---- P3: fold  fps = sum_ks fp[ks] ----
    if (gtid < 40000) {
        const floatx4* f4 = (const floatx4*)fp;
        floatx4 s = f4[gtid];
        #pragma unroll
        for (int ks = 1; ks < 8; ++ks) {
            floatx4 u = f4[(size_t)ks * 40000 + gtid];
            s.x += u.x; s.y += u.y; s.z += u.z; s.w += u.w;
        }
        *(floatx4*)(fps + (size_t)gtid * 4) = s;
    }
    grid.sync();

    // ---- P4: score (exact R2 score_k) ----
    {
        int b   = bx >> 5;
        int rem = bx & 31;
        int it  = rem >> 1;
        int jh  = rem & 1;
        int i0  = it * 32;

        if (t < 32) {
            int2 ii = *(const int2*)(ind0 + ((size_t)b * NT + i0 + t) * 2);
            a0s[t] = ii.x;
            a1s[t] = ii.y + 50;
        }
        {
            int2 jj = *(const int2*)(ind1 + ((size_t)b * NT + jh * 256 + t) * 2);
            c0s[t] = jj.x;
            c1s[t] = jj.y + 50;
        }
        __syncthreads();

        const float* fb = fps + (size_t)b * (XDIM * XDIM);
        for (int idx = t; idx < 1024; idx += 256) {
            int il = idx >> 5, yq = idx & 31;
            if (yq < 25) {
                floatx4 u = *(const floatx4*)(fb + a0s[il] * XDIM + yq * 4);
                floatx4 w = *(const floatx4*)(fb + a1s[il] * XDIM + yq * 4);
                floatx4 s;
                s.x = u.x + w.x; s.y = u.y + w.y;
                s.z = u.z + w.z; s.w = u.w + w.w;
                *(floatx4*)&rowsum[il][yq * 4] = s;
            }
        }
        __syncthreads();

        float* sout = out + (size_t)b * (NT * NT) + (size_t)i0 * NT + jh * 256;
        for (int o = t; o < 8192; o += 256) {
            int il = o >> 8, jl = o & 255;
            float val = rowsum[il][c0s[jl]] + rowsum[il][c1s[jl]];
            __builtin_nontemporal_store(val, &sout[(size_t)il * NT + jl]);
        }
    }
}

// ---------------------------------------------------------------------------
extern "C" void kernel_launch(void* const* d_in, const int* in_sizes, int n_in,
                              void* d_out, int out_size, void* d_ws, size_t ws_size,
                              hipStream_t stream) {
    const float* fea  = (const float*)d_in[0];
    const int*   ind0 = (const int*)d_in[1];
    const int*   ind1 = (const int*)d_in[2];
    const float* W0   = (const float*)d_in[3];
    const float* W1   = (const float*)d_in[4];
    const float* bias = (const float*)d_in[5];
    const float* v    = (const float*)d_in[6];
    float* out = (float*)d_out;
    char*  ws  = (char*)d_ws;

    _Float16* Wt2   = (_Float16*)(ws + WS_WT2);
    _Float16* fea16 = (_Float16*)(ws + WS_FEA16);
    _Float16* v16   = (_Float16*)(ws + WS_V16);
    _Float16* h16   = (_Float16*)(ws + WS_H16);
    float*    fp    = (float*)(ws + WS_FP);
    float*    fps   = (float*)(ws + WS_FPS);
    float*    pout  = (float*)(out + (size_t)16 * NT * NT);

    void* args[] = {(void*)&fea, (void*)&ind0, (void*)&ind1, (void*)&W0,
                    (void*)&W1, (void*)&bias, (void*)&v,
                    (void*)&Wt2, (void*)&fea16, (void*)&v16, (void*)&h16,
                    (void*)&fp, (void*)&fps, (void*)&out, (void*)&pout};
    hipLaunchCooperativeKernel((void*)fused_k, dim3(512), dim3(256), args, 0, stream);
}

// Round 5
// 117.768 us; speedup vs baseline: 3.1767x; 3.1767x over previous
//
#include <hip/hip_runtime.h>

// Problem constants
#define XDIM  100       // HK*BAG
#define DDIM  512
#define HDIM  512
#define NT    512
// ws layout (bytes)
#define WS_WT2   0          // fp16 Wt2[2][16][512][4][8]   = 1,048,576 B
#define WS_FEA16 1048576    // fp16 fea16[3200][512]        = 3,276,800 B
#define WS_V16   4325376    // fp16 v16[512]                = 1,024 B
#define WS_H16   4326400    // fp16 h16[3200][512]          = 3,276,800 B
#define WS_FP    7603200    // fp32 fp[8][16][100][100]     = 5,120,000 B
#define WS_FPS   12723200   // fp32 fps[16][100][100]       = 640,000 B

typedef _Float16 h16x8 __attribute__((ext_vector_type(8)));
typedef _Float16 h2    __attribute__((ext_vector_type(2)));
typedef float floatx4  __attribute__((ext_vector_type(4)));
typedef float floatx2  __attribute__((ext_vector_type(2)));

union H8U { h16x8 v; h2 p[4]; unsigned u[4]; };

// ---------------------------------------------------------------------------
// prep: Wt2 (mfma-B-fragment-ordered fp16 weights), fea16, v16
__global__ void __launch_bounds__(256) prep_k(const float* __restrict__ W0,
                                              const float* __restrict__ W1,
                                              const float* __restrict__ fea,
                                              const float* __restrict__ v,
                                              _Float16* __restrict__ Wt2,
                                              _Float16* __restrict__ fea16,
                                              _Float16* __restrict__ v16) {
    int blk = blockIdx.x;
    int t = threadIdx.x;
    if (blk < 2048) {
        // Wt2[w][kb][c][q][8] = W[d=kb*32+q*8+j][c]
        int o  = blk * 256 + t;
        int w  = o >> 18;
        int kb = (o >> 14) & 15;
        int c  = (o >> 5) & 511;
        int qj = o & 31;
        int d  = kb * 32 + qj;
        const float* W = w ? W1 : W0;
        Wt2[o] = (_Float16)W[d * 512 + c];
    } else if (blk < 3648) {
        int tid = (blk - 2048) * 256 + t;    // 409600 threads, 4 elems each
        float4 x = *(const float4*)(fea + (size_t)tid * 4);
        _Float16 r[4] = {(_Float16)x.x, (_Float16)x.y, (_Float16)x.z, (_Float16)x.w};
        *(uint2*)(fea16 + (size_t)tid * 4) = *(const uint2*)r;
    } else {
        v16[t * 2]     = (_Float16)v[t * 2];
        v16[t * 2 + 1] = (_Float16)v[t * 2 + 1];
    }
}

// ---------------------------------------------------------------------------
// gemm: h16[hb][m][c] = sum_d fea16[hb][m][d] * W{s}[d][c] (+bias if s==1)
// 64m x 64n tile: all 4 waves read the SAME 64 B-cols (L1/L2 reuse within
// block; Wt2 L2 traffic 122 MB -> 67 MB). Rows mt*36+w*16 cover 0..99
// exactly; 36-row overlap recomputes bit-identical values (benign dup store).
__global__ void __launch_bounds__(256) gemm_k(const _Float16* __restrict__ fea16,
                                              const _Float16* __restrict__ Wt2,
                                              const float* __restrict__ bias,
                                              _Float16* __restrict__ h16) {
    int bx   = blockIdx.x;          // 512 = 32 hb * 2 mt * 8 no
    int hb   = bx >> 4;
    int mt   = (bx >> 3) & 1;
    int no   = bx & 7;
    int w    = threadIdx.x >> 6;
    int lane = threadIdx.x & 63;
    int n0   = no * 64;
    int m0   = mt * 36 + w * 16;    // 0..84; +15 stays < 100
    int s    = hb & 1;
    int l15  = lane & 15;
    int q    = lane >> 4;

    const _Float16* ap = fea16 + (size_t)hb * (XDIM * DDIM) + (size_t)(m0 + l15) * DDIM + q * 8;
    const _Float16* bp = Wt2 + (size_t)s * 262144 + (size_t)(n0 + l15) * 32 + q * 8;

    floatx4 acc0 = {0.f, 0.f, 0.f, 0.f};
    floatx4 acc1 = acc0, acc2 = acc0, acc3 = acc0;

    for (int kb = 0; kb < 16; ++kb) {
        h16x8 a = *(const h16x8*)(ap + kb * 32);
        const _Float16* bkb = bp + kb * 16384;
        h16x8 b0 = *(const h16x8*)(bkb);
        h16x8 b1 = *(const h16x8*)(bkb + 512);
        h16x8 b2 = *(const h16x8*)(bkb + 1024);
        h16x8 b3 = *(const h16x8*)(bkb + 1536);
        acc0 = __builtin_amdgcn_mfma_f32_16x16x32_f16(a, b0, acc0, 0, 0, 0);
        acc1 = __builtin_amdgcn_mfma_f32_16x16x32_f16(a, b1, acc1, 0, 0, 0);
        acc2 = __builtin_amdgcn_mfma_f32_16x16x32_f16(a, b2, acc2, 0, 0, 0);
        acc3 = __builtin_amdgcn_mfma_f32_16x16x32_f16(a, b3, acc3, 0, 0, 0);
    }

    _Float16* hob = h16 + (size_t)hb * (XDIM * HDIM);
    #pragma unroll
    for (int j = 0; j < 4; ++j) {
        floatx4 a = (j == 0) ? acc0 : (j == 1) ? acc1 : (j == 2) ? acc2 : acc3;
        int col = n0 + 16 * j + l15;
        float bi = s ? bias[col] : 0.f;
        #pragma unroll
        for (int r = 0; r < 4; ++r) {
            int mr = m0 + q * 4 + r;  // always < 100
            hob[(size_t)mr * HDIM + col] = (_Float16)(a[r] + bi);
        }
    }
}

// ---------------------------------------------------------------------------
// full: fp[ks][b][x][y] = sum_{h in chunk ks} relu(h0[x,h]+h1[y,h])*v[h]
// 64x64 tile / block, 4x4 per thread, packed fp16 + v_dot2. Also writes pairs.
__global__ void __launch_bounds__(256) full_k(const _Float16* __restrict__ h16,
                                              const _Float16* __restrict__ v16,
                                              float* __restrict__ fp,
                                              float* __restrict__ pout) {
    int bx  = blockIdx.x;           // 512 = 8 ks * 16 b * 2 xt * 2 yt
    int ks  = bx >> 6;
    int rem = bx & 63;
    int b   = rem >> 2;
    int xt  = (rem >> 1) & 1;
    int yt  = rem & 1;
    int x0  = xt * 36;              // tiles [0,64) and [36,100): overlap writes same values
    int y0  = yt * 36;
    int kc  = ks * 64;

    __shared__ _Float16 sh0[64][72];      // [x][k], stride 72 fp16 (bank-safe)
    __shared__ unsigned sh1p[32][64];     // [kpair][y] packed h2
    __shared__ unsigned sv[32];           // v pairs

    int t = threadIdx.x;
    int r = t & 63, kseg = t >> 6;

    const _Float16* g0 = h16 + ((size_t)(b * 2) * XDIM + x0 + r) * HDIM + kc + kseg * 16;
    *(h16x8*)&sh0[r][kseg * 16]     = *(const h16x8*)g0;
    *(h16x8*)&sh0[r][kseg * 16 + 8] = *(const h16x8*)(g0 + 8);

    const _Float16* g1 = h16 + ((size_t)(b * 2 + 1) * XDIM + y0 + r) * HDIM + kc + kseg * 16;
    H8U u0, u1;
    u0.v = *(const h16x8*)g1;
    u1.v = *(const h16x8*)(g1 + 8);
    #pragma unroll
    for (int pp = 0; pp < 4; ++pp) {
        sh1p[kseg * 8 + pp][r]     = u0.u[pp];
        sh1p[kseg * 8 + 4 + pp][r] = u1.u[pp];
    }
    if (t < 32) sv[t] = *(const unsigned*)(v16 + kc + t * 2);
    __syncthreads();

    // pairs meshgrid: pure streaming stores (nontemporal: keep L2 for fp/h16),
    // drain under the compute below
    {
        size_t pbase = (size_t)bx * 8192;
        #pragma unroll 4
        for (int i = 0; i < 32; ++i) {
            unsigned idx = (unsigned)(pbase + i * 256 + t);
            floatx2 pr;
            pr.x = (float)((idx >> 9) & 511);
            pr.y = (float)(idx & 511);
            __builtin_nontemporal_store(pr, (floatx2*)(pout + (size_t)idx * 2));
        }
    }

    int ty = t >> 4, tx = t & 15;
    float acc[4][4] = {};
    h2 hz; hz[0] = (_Float16)0; hz[1] = (_Float16)0;

    for (int kk = 0; kk < 8; ++kk) {
        H8U a[4];
        #pragma unroll
        for (int i = 0; i < 4; ++i)
            a[i].v = *(const h16x8*)&sh0[ty * 4 + i][kk * 8];
        uint4 bq[4];
        #pragma unroll
        for (int p = 0; p < 4; ++p)
            bq[p] = *(const uint4*)&sh1p[kk * 4 + p][tx * 4];
        uint4 vq = *(const uint4*)&sv[kk * 4];
        const unsigned* vqa = (const unsigned*)&vq;

        #pragma unroll
        for (int p = 0; p < 4; ++p) {
            h2 vp = __builtin_bit_cast(h2, vqa[p]);
            const unsigned* bqa = (const unsigned*)&bq[p];
            #pragma unroll
            for (int i = 0; i < 4; ++i) {
                h2 av = a[i].p[p];
                #pragma unroll
                for (int j = 0; j < 4; ++j) {
                    h2 s = av + __builtin_bit_cast(h2, bqa[j]);
                    s = __builtin_elementwise_max(s, hz);
#if __has_builtin(__builtin_amdgcn_fdot2)
                    acc[i][j] = __builtin_amdgcn_fdot2(s, vp, acc[i][j], false);
#else
                    acc[i][j] += (float)s[0] * (float)vp[0] + (float)s[1] * (float)vp[1];
#endif
                }
            }
        }
    }

    float* fpb = fp + (size_t)(ks * 16 + b) * (XDIM * XDIM);
    #pragma unroll
    for (int i = 0; i < 4; ++i) {
        floatx4 o;
        o.x = acc[i][0]; o.y = acc[i][1]; o.z = acc[i][2]; o.w = acc[i][3];
        *(floatx4*)&fpb[(size_t)(x0 + ty * 4 + i) * XDIM + y0 + tx * 4] = o;
    }
}

// ---------------------------------------------------------------------------
// fold: fps[b][x][y] = sum_ks fp[ks][b][x][y]  (5.12 MB read, 640 KB write)
__global__ void __launch_bounds__(256) fold_k(const float* __restrict__ fp,
                                              float* __restrict__ fps) {
    int vi = blockIdx.x * 256 + threadIdx.x;     // float4 index, 40000 total
    if (vi >= 40000) return;
    const floatx4* f4 = (const floatx4*)fp;
    floatx4 s = f4[vi];
    #pragma unroll
    for (int ks = 1; ks < 8; ++ks) {
        floatx4 u = f4[(size_t)ks * 40000 + vi];
        s.x += u.x; s.y += u.y; s.z += u.z; s.w += u.w;
    }
    *(floatx4*)(fps + (size_t)vi * 4) = s;
}

// ---------------------------------------------------------------------------
// score: pooled[b][i][j] = rowsum_i(c0[j]) + rowsum_i(c1[j]),
//        rowsum_i = fps[b][a0[i]][:] + fps[b][a1[i]][:]
__global__ void __launch_bounds__(256) score_k(const float* __restrict__ fps,
                                               const int* __restrict__ ind0,
                                               const int* __restrict__ ind1,
                                               float* __restrict__ out) {
    int bx  = blockIdx.x;           // 512 = 16 b * 16 itiles * 2 jhalves
    int b   = bx >> 5;
    int rem = bx & 31;
    int it  = rem >> 1;
    int jh  = rem & 1;
    int i0  = it * 32;

    __shared__ float rowsum[32][100];
    __shared__ int a0s[32], a1s[32];
    __shared__ int c0s[256], c1s[256];

    int t = threadIdx.x;
    if (t < 32) {
        int2 ii = *(const int2*)(ind0 + ((size_t)b * NT + i0 + t) * 2);
        a0s[t] = ii.x;
        a1s[t] = ii.y + 50;
    }
    {
        int2 jj = *(const int2*)(ind1 + ((size_t)b * NT + jh * 256 + t) * 2);
        c0s[t] = jj.x;
        c1s[t] = jj.y + 50;
    }
    __syncthreads();

    const float* fb = fps + (size_t)b * (XDIM * XDIM);
    for (int idx = t; idx < 1024; idx += 256) {
        int il = idx >> 5, yq = idx & 31;
        if (yq < 25) {
            floatx4 u = *(const floatx4*)(fb + a0s[il] * XDIM + yq * 4);
            floatx4 w = *(const floatx4*)(fb + a1s[il] * XDIM + yq * 4);
            floatx4 s;
            s.x = u.x + w.x; s.y = u.y + w.y;
            s.z = u.z + w.z; s.w = u.w + w.w;
            *(floatx4*)&rowsum[il][yq * 4] = s;
        }
    }
    __syncthreads();

    float* sout = out + (size_t)b * (NT * NT) + (size_t)i0 * NT + jh * 256;
    for (int o = t; o < 8192; o += 256) {
        int il = o >> 8, jl = o & 255;
        float val = rowsum[il][c0s[jl]] + rowsum[il][c1s[jl]];
        __builtin_nontemporal_store(val, &sout[(size_t)il * NT + jl]);
    }
}

// ---------------------------------------------------------------------------
extern "C" void kernel_launch(void* const* d_in, const int* in_sizes, int n_in,
                              void* d_out, int out_size, void* d_ws, size_t ws_size,
                              hipStream_t stream) {
    const float* fea  = (const float*)d_in[0];
    const int*   ind0 = (const int*)d_in[1];
    const int*   ind1 = (const int*)d_in[2];
    const float* W0   = (const float*)d_in[3];
    const float* W1   = (const float*)d_in[4];
    const float* bias = (const float*)d_in[5];
    const float* v    = (const float*)d_in[6];
    float* out = (float*)d_out;
    char*  ws  = (char*)d_ws;

    _Float16* Wt2   = (_Float16*)(ws + WS_WT2);
    _Float16* fea16 = (_Float16*)(ws + WS_FEA16);
    _Float16* v16   = (_Float16*)(ws + WS_V16);
    _Float16* h16   = (_Float16*)(ws + WS_H16);
    float*    fp    = (float*)(ws + WS_FP);
    float*    fps   = (float*)(ws + WS_FPS);
    float*    pout  = (float*)(out + (size_t)16 * NT * NT);

    hipLaunchKernelGGL(prep_k,  dim3(3649), dim3(256), 0, stream, W0, W1, fea, v, Wt2, fea16, v16);
    hipLaunchKernelGGL(gemm_k,  dim3(512),  dim3(256), 0, stream, fea16, Wt2, bias, h16);
    hipLaunchKernelGGL(full_k,  dim3(512),  dim3(256), 0, stream, h16, v16, fp, pout);
    hipLaunchKernelGGL(fold_k,  dim3(157),  dim3(256), 0, stream, fp, fps);
    hipLaunchKernelGGL(score_k, dim3(512),  dim3(256), 0, stream, fps, ind0, ind1, out);
}